// Round 3
// baseline (109.355 us; speedup 1.0000x reference)
//
#include <hip/hip_runtime.h>
#include <hip/hip_cooperative_groups.h>

namespace cg = cooperative_groups;

#define BSZ 4
#define CH  64
#define CE  8      // C/8
#define HW  4096
#define NBLK 256   // 4 batches x 64 column-groups
#define PJ  1088   // partials per block: A 512 + B 512 + S 64

// ---------------------------------------------------------------------------
// Single cooperative kernel, 256 blocks x 256 threads (1 block/CU).
// Phase 1 (per block = (b, 64 columns)):
//   - 1x1 convs: k(8), q_l(8), v(64) for its columns (weights via s_load).
//   - k,q_l -> global (needed at other positions in phase 2); v -> LDS only.
//   - block-partial reduction over its 64 q's:
//       Ap[c,e] = sum_q v[c,q]*qg_w[q,e]
//       Bp[c,e] = sum_q v[c,q]*k[e,q]
//       Sp[c]   = sum_q v[c,q]*qg_b[q]
//     written to this block's own Pbuf slot (no atomics, no memset).
// grid.sync()
// Phase 2 (same block):
//   - reduce the 64 partial slots of its batch -> red[1088] in LDS.
//   - out[b,c,p] = gg*(dot8(k_g[p],A[c]) + S[c]) + gl*dot8(q_l[p],B[c]) + x.
//     k_g[b,p,e] = kbuf flat at b*32768 + p*8 + e (raw reshape regroup).
// ---------------------------------------------------------------------------
__global__ __launch_bounds__(256, 1) void fused_kernel(
    const float* __restrict__ x,
    const float* __restrict__ qlw, const float* __restrict__ qlb,
    const float* __restrict__ kw,  const float* __restrict__ kb,
    const float* __restrict__ vw,  const float* __restrict__ vb,
    const float* __restrict__ qgw, const float* __restrict__ qgb,
    const float* __restrict__ ggp, const float* __restrict__ glp,
    float* __restrict__ kbuf, float* __restrict__ qlbuf,
    float* __restrict__ Pbuf, float* __restrict__ out)
{
    __shared__ float v_lds[CH][65];   // (c+lane)%32 banks -> 2-way max (free)
    __shared__ float k_lds[CE][64];
    __shared__ float red[PJ];

    const int tid  = threadIdx.x;
    const int lane = tid & 63;
    const int g    = __builtin_amdgcn_readfirstlane(tid >> 6);  // wave 0..3
    const int b    = blockIdx.x >> 6;
    const int p0   = (blockIdx.x & 63) << 6;
    const int p    = p0 | lane;

    // ---------------- phase 1: conv (20 output channels per wave) ----------
    float xv[CH];
#pragma unroll
    for (int c = 0; c < CH; ++c) xv[c] = x[((b << 6) + c) * HW + p];

    if (g == 0) {
#pragma unroll
        for (int o = 0; o < CE; ++o) {
            float acc = kb[o];
#pragma unroll
            for (int c = 0; c < CH; ++c) acc += kw[o * CH + c] * xv[c];
            kbuf[((b << 3) + o) * HW + p] = acc;
            k_lds[o][lane] = acc;
        }
#pragma unroll
        for (int o = 0; o < CE; ++o) {
            float acc = qlb[o];
#pragma unroll
            for (int c = 0; c < CH; ++c) acc += qlw[o * CH + c] * xv[c];
            qlbuf[((b << 3) + o) * HW + p] = acc;
        }
#pragma unroll
        for (int o = 0; o < 4; ++o) {
            float acc = vb[o];
#pragma unroll
            for (int c = 0; c < CH; ++c) acc += vw[o * CH + c] * xv[c];
            v_lds[o][lane] = acc;
        }
    } else {
        const int c0 = 4 + (g - 1) * 20;   // scalar: 4..23 / 24..43 / 44..63
#pragma unroll
        for (int oi = 0; oi < 20; ++oi) {
            const int o = c0 + oi;         // scalar
            float acc = vb[o];
#pragma unroll
            for (int cc = 0; cc < CH; ++cc) acc += vw[o * CH + cc] * xv[cc];
            v_lds[o][lane] = acc;
        }
    }
    __syncthreads();

    // ---------------- phase 1b: block-partial A/B/S ------------------------
    {
        const int c  = lane;
        const int e0 = g;        // scalar
        const int e1 = g + 4;    // scalar
        float a0 = 0.f, a1 = 0.f, b0 = 0.f, b1 = 0.f, s = 0.f;
#pragma unroll
        for (int pp = 0; pp < 64; ++pp) {
            const float vv = v_lds[c][pp];          // 2-way banked: free
            a0 += vv * qgw[(p0 + pp) * 8 + e0];     // s_load (uniform addr)
            a1 += vv * qgw[(p0 + pp) * 8 + e1];
            b0 += vv * k_lds[e0][pp];               // LDS broadcast
            b1 += vv * k_lds[e1][pp];
            if (g == 0) s += vv * qgb[p0 + pp];     // wave-uniform branch
        }
        float* P = Pbuf + (size_t)blockIdx.x * PJ;
        P[(c << 3) + e0] = a0;
        P[(c << 3) + e1] = a1;
        P[512 + (c << 3) + e0] = b0;
        P[512 + (c << 3) + e1] = b1;
        if (g == 0) P[1024 + c] = s;
    }

    __threadfence();
    cg::this_grid().sync();

    // ---------------- phase 2a: reduce partials of this batch --------------
    for (int j = tid; j < PJ; j += 256) {
        const float* P = Pbuf + (size_t)(b << 6) * PJ + j;
        float acc = 0.f;
#pragma unroll 8
        for (int cg2 = 0; cg2 < 64; ++cg2) acc += P[(size_t)cg2 * PJ];
        red[j] = acc;                                // coalesced loads per iter
    }
    __syncthreads();

    // ---------------- phase 2b: rank-8 combine + residual ------------------
    const float gg = ggp[0], gl = glp[0];

    const float* kgp = kbuf + ((size_t)(b << 3) * HW) + ((size_t)p << 3);
    const float4 kg0 = *reinterpret_cast<const float4*>(kgp);
    const float4 kg1 = *reinterpret_cast<const float4*>(kgp + 4);
    const float kg[8] = {kg0.x, kg0.y, kg0.z, kg0.w, kg1.x, kg1.y, kg1.z, kg1.w};
    float ql[8];
#pragma unroll
    for (int e = 0; e < CE; ++e) ql[e] = qlbuf[((b << 3) + e) * HW + p];

    const int c0 = g << 4;   // scalar
#pragma unroll
    for (int ci = 0; ci < 16; ++ci) {
        const int c = c0 + ci;   // scalar
        float aA = 0.f, aB = 0.f;
#pragma unroll
        for (int e = 0; e < CE; ++e) {
            aA += kg[e] * red[(c << 3) + e];         // LDS broadcast
            aB += ql[e] * red[512 + (c << 3) + e];
        }
        const int idx = ((b << 6) + c) * HW + p;
        out[idx] = gg * (aA + red[1024 + c]) + gl * aB + x[idx];
    }
}

extern "C" void kernel_launch(void* const* d_in, const int* in_sizes, int n_in,
                              void* d_out, int out_size, void* d_ws, size_t ws_size,
                              hipStream_t stream) {
    const float* x   = (const float*)d_in[0];
    const float* qlw = (const float*)d_in[1];
    const float* qlb = (const float*)d_in[2];
    const float* kw  = (const float*)d_in[3];
    const float* kb  = (const float*)d_in[4];
    const float* vw  = (const float*)d_in[5];
    const float* vb  = (const float*)d_in[6];
    const float* qgw = (const float*)d_in[7];
    const float* qgb = (const float*)d_in[8];
    const float* gg  = (const float*)d_in[9];
    const float* gl  = (const float*)d_in[10];
    float* out = (float*)d_out;

    float* ws    = (float*)d_ws;
    float* kbuf  = ws;                        // 4*8*4096   = 131072 f
    float* qlbuf = kbuf + BSZ * CE * HW;      // 131072 f
    float* Pbuf  = qlbuf + BSZ * CE * HW;     // 256*1088   = 278528 f
    // total ~2.2 MB workspace

    void* args[] = {
        (void*)&x, (void*)&qlw, (void*)&qlb, (void*)&kw, (void*)&kb,
        (void*)&vw, (void*)&vb, (void*)&qgw, (void*)&qgb, (void*)&gg,
        (void*)&gl, (void*)&kbuf, (void*)&qlbuf, (void*)&Pbuf, (void*)&out
    };
    hipLaunchCooperativeKernel((void*)fused_kernel, dim3(NBLK), dim3(256),
                               args, 0, stream);
}

// Round 4
// 35.549 us; speedup vs baseline: 3.0762x; 3.0762x over previous
//
#include <hip/hip_runtime.h>

#define BSZ 4
#define CH  64
#define CE  8      // C/8
#define HW  4096
#define PJ  1088   // per-block partials: A 512 + B 512 + S 64

// ---------------------------------------------------------------------------
// K1: per block = (batch b, 64 columns p0..p0+63).
//  - stage all 1x1 weights (80x64) + qg slice in LDS once
//  - conv: each thread holds x column in regs; weights read as b128
//    broadcasts (wave-uniform address -> conflict-free)
//  - k(8), q_l(8) -> global (needed at other positions later); v -> LDS only
//  - block-partial A/B/S over this block's 64 q's -> own Pbuf slot
//    (no atomics, no memset, coalesced stores)
// ---------------------------------------------------------------------------
__global__ __launch_bounds__(256) void k1_kernel(
    const float* __restrict__ x,
    const float* __restrict__ qlw, const float* __restrict__ qlb,
    const float* __restrict__ kw,  const float* __restrict__ kb,
    const float* __restrict__ vw,  const float* __restrict__ vb,
    const float* __restrict__ qgw, const float* __restrict__ qgb,
    float* __restrict__ kbuf, float* __restrict__ qlbuf, float* __restrict__ Pbuf)
{
    __shared__ float w_lds[80 * 64];     // rows: 0-7 kw, 8-15 qlw, 16-79 vw
    __shared__ float b_lds[80];
    __shared__ float vT[64][65];         // vT[pp][c], 2-way banks max
    __shared__ float kT[CE][64];         // kT[e][pp], b128-aligned rows
    __shared__ float qgT[CE][64];        // qgT[e][pp]
    __shared__ float qgbl[64];

    const int tid  = threadIdx.x;
    const int lane = tid & 63;
    const int g    = __builtin_amdgcn_readfirstlane(tid >> 6);  // wave 0..3
    const int b    = blockIdx.x >> 6;
    const int p0   = (blockIdx.x & 63) << 6;
    const int p    = p0 | lane;

    // ---- stage weights / qg slice (coalesced) ----
    for (int i = tid; i < 80 * 64; i += 256) {
        const int o = i >> 6, c = i & 63;
        float w;
        if (o < 8)       w = kw[(o << 6) + c];
        else if (o < 16) w = qlw[((o - 8) << 6) + c];
        else             w = vw[((o - 16) << 6) + c];
        w_lds[i] = w;
    }
    if (tid < 80)
        b_lds[tid] = (tid < 8) ? kb[tid] : (tid < 16 ? qlb[tid - 8] : vb[tid - 16]);
    for (int i = tid; i < 512; i += 256) {          // qgT[e][pp]
        const int pp = i >> 3, e = i & 7;
        qgT[e][pp] = qgw[((p0 + pp) << 3) + e];
    }
    if (tid < 64) qgbl[tid] = qgb[p0 + tid];

    // ---- x column into registers (64 coalesced loads) ----
    float xv[CH];
#pragma unroll
    for (int c = 0; c < CH; ++c) xv[c] = x[(((b << 6) + c) << 12) + p];

    __syncthreads();

    // ---- conv: wave 0 -> k(8)+ql(8)+v(0..3); waves 1-3 -> 20 v channels ----
    if (g == 0) {
#pragma unroll
        for (int o = 0; o < CE; ++o) {
            float acc = b_lds[o];
            const float* wr = &w_lds[o << 6];
#pragma unroll
            for (int c = 0; c < CH; c += 4) {
                const float4 w4 = *reinterpret_cast<const float4*>(wr + c);
                acc += w4.x * xv[c] + w4.y * xv[c + 1]
                     + w4.z * xv[c + 2] + w4.w * xv[c + 3];
            }
            kbuf[(((b << 3) + o) << 12) + p] = acc;
            kT[o][lane] = acc;
        }
#pragma unroll
        for (int o = 0; o < CE; ++o) {
            float acc = b_lds[8 + o];
            const float* wr = &w_lds[(8 + o) << 6];
#pragma unroll
            for (int c = 0; c < CH; c += 4) {
                const float4 w4 = *reinterpret_cast<const float4*>(wr + c);
                acc += w4.x * xv[c] + w4.y * xv[c + 1]
                     + w4.z * xv[c + 2] + w4.w * xv[c + 3];
            }
            qlbuf[(((b << 3) + o) << 12) + p] = acc;
        }
#pragma unroll
        for (int o = 0; o < 4; ++o) {
            float acc = b_lds[16 + o];
            const float* wr = &w_lds[(16 + o) << 6];
#pragma unroll
            for (int c = 0; c < CH; c += 4) {
                const float4 w4 = *reinterpret_cast<const float4*>(wr + c);
                acc += w4.x * xv[c] + w4.y * xv[c + 1]
                     + w4.z * xv[c + 2] + w4.w * xv[c + 3];
            }
            vT[lane][o] = acc;
        }
    } else {
        const int c0 = 4 + (g - 1) * 20;   // scalar
#pragma unroll
        for (int oi = 0; oi < 20; ++oi) {
            const int o = c0 + oi;         // scalar
            float acc = b_lds[16 + o];
            const float* wr = &w_lds[(16 + o) << 6];
#pragma unroll
            for (int c = 0; c < CH; c += 4) {
                const float4 w4 = *reinterpret_cast<const float4*>(wr + c);
                acc += w4.x * xv[c] + w4.y * xv[c + 1]
                     + w4.z * xv[c + 2] + w4.w * xv[c + 3];
            }
            vT[lane][o] = acc;
        }
    }
    __syncthreads();

    // ---- block-partial A/B/S: thread (c=lane) x (e0=g, e1=g+4) ----
    {
        const int e0 = g, e1 = g + 4;      // scalar
        float a0 = 0.f, a1 = 0.f, bb0 = 0.f, bb1 = 0.f, s = 0.f;
#pragma unroll
        for (int pp = 0; pp < 64; pp += 4) {
            const float4 kk0 = *reinterpret_cast<const float4*>(&kT[e0][pp]);
            const float4 kk1 = *reinterpret_cast<const float4*>(&kT[e1][pp]);
            const float4 qq0 = *reinterpret_cast<const float4*>(&qgT[e0][pp]);
            const float4 qq1 = *reinterpret_cast<const float4*>(&qgT[e1][pp]);
            const float v0 = vT[pp + 0][lane];
            const float v1 = vT[pp + 1][lane];
            const float v2 = vT[pp + 2][lane];
            const float v3 = vT[pp + 3][lane];
            a0  += v0 * qq0.x + v1 * qq0.y + v2 * qq0.z + v3 * qq0.w;
            a1  += v0 * qq1.x + v1 * qq1.y + v2 * qq1.z + v3 * qq1.w;
            bb0 += v0 * kk0.x + v1 * kk0.y + v2 * kk0.z + v3 * kk0.w;
            bb1 += v0 * kk1.x + v1 * kk1.y + v2 * kk1.z + v3 * kk1.w;
            if (g == 0) {                   // wave-uniform
                const float4 qb = *reinterpret_cast<const float4*>(&qgbl[pp]);
                s += v0 * qb.x + v1 * qb.y + v2 * qb.z + v3 * qb.w;
            }
        }
        // P layout: A[e][c] (0..511), B[e][c] (512..1023), S[c] (1024..1087)
        float* P = Pbuf + (size_t)blockIdx.x * PJ;
        P[(e0 << 6) + lane] = a0;                 // coalesced
        P[(e1 << 6) + lane] = a1;
        P[512 + (e0 << 6) + lane] = bb0;
        P[512 + (e1 << 6) + lane] = bb1;
        if (g == 0) P[1024 + lane] = s;
    }
}

// ---------------------------------------------------------------------------
// K2: per block = (batch b, 64 columns).
//  Phase A: reduce the 64 partial slots of this batch -> sA/sB/sS in LDS
//           (gg/gl folded in).
//  Phase B: out[b,c,p] = dot8(kg[p], ggA[c]) + ggS[c] + dot8(ql[p], glB[c]) + x
// ---------------------------------------------------------------------------
__global__ __launch_bounds__(256) void k2_kernel(
    const float* __restrict__ x,
    const float* __restrict__ kbuf, const float* __restrict__ qlbuf,
    const float* __restrict__ Pbuf,
    const float* __restrict__ ggp, const float* __restrict__ glp,
    float* __restrict__ out)
{
    __shared__ float sA[CH][8], sB[CH][8], sS[CH];
    const int tid  = threadIdx.x;
    const int lane = tid & 63;
    const int g    = __builtin_amdgcn_readfirstlane(tid >> 6);
    const int b    = blockIdx.x >> 6;
    const int p    = ((blockIdx.x & 63) << 6) | lane;
    const float gg = ggp[0], gl = glp[0];

    const float* Pb = Pbuf + (size_t)(b << 6) * PJ;
    for (int j = tid; j < PJ; j += 256) {
        float acc = 0.f;
#pragma unroll 16
        for (int s2 = 0; s2 < 64; ++s2) acc += Pb[(size_t)s2 * PJ + j];
        if (j < 512)       sA[j & 63][j >> 6] = gg * acc;
        else if (j < 1024) sB[j & 63][(j - 512) >> 6] = gl * acc;
        else               sS[j - 1024] = gg * acc;
    }

    // independent of LDS: start these loads before the barrier
    const float* kgp = kbuf + ((size_t)b << 15) + ((size_t)p << 3);
    const float4 kg0 = *reinterpret_cast<const float4*>(kgp);
    const float4 kg1 = *reinterpret_cast<const float4*>(kgp + 4);
    float ql[CE];
#pragma unroll
    for (int e = 0; e < CE; ++e) ql[e] = qlbuf[(((b << 3) + e) << 12) + p];

    __syncthreads();

    const int c0 = g << 4;   // scalar
#pragma unroll
    for (int ci = 0; ci < 16; ++ci) {
        const int c = c0 + ci;   // scalar
        const float4 A0 = *reinterpret_cast<const float4*>(&sA[c][0]);
        const float4 A1 = *reinterpret_cast<const float4*>(&sA[c][4]);
        const float4 B0 = *reinterpret_cast<const float4*>(&sB[c][0]);
        const float4 B1 = *reinterpret_cast<const float4*>(&sB[c][4]);
        float r = sS[c];
        r += kg0.x * A0.x + kg0.y * A0.y + kg0.z * A0.z + kg0.w * A0.w;
        r += kg1.x * A1.x + kg1.y * A1.y + kg1.z * A1.z + kg1.w * A1.w;
        r += ql[0] * B0.x + ql[1] * B0.y + ql[2] * B0.z + ql[3] * B0.w;
        r += ql[4] * B1.x + ql[5] * B1.y + ql[6] * B1.z + ql[7] * B1.w;
        const int idx = (((b << 6) + c) << 12) + p;
        out[idx] = r + x[idx];
    }
}

extern "C" void kernel_launch(void* const* d_in, const int* in_sizes, int n_in,
                              void* d_out, int out_size, void* d_ws, size_t ws_size,
                              hipStream_t stream) {
    const float* x   = (const float*)d_in[0];
    const float* qlw = (const float*)d_in[1];
    const float* qlb = (const float*)d_in[2];
    const float* kw  = (const float*)d_in[3];
    const float* kb  = (const float*)d_in[4];
    const float* vw  = (const float*)d_in[5];
    const float* vb  = (const float*)d_in[6];
    const float* qgw = (const float*)d_in[7];
    const float* qgb = (const float*)d_in[8];
    const float* gg  = (const float*)d_in[9];
    const float* gl  = (const float*)d_in[10];
    float* out = (float*)d_out;

    float* ws    = (float*)d_ws;
    float* kbuf  = ws;                        // 4*8*4096 = 131072 f
    float* qlbuf = kbuf + BSZ * CE * HW;      // 131072 f
    float* Pbuf  = qlbuf + BSZ * CE * HW;     // 256*1088 = 278528 f

    k1_kernel<<<256, 256, 0, stream>>>(x, qlw, qlb, kw, kb, vw, vb, qgw, qgb,
                                       kbuf, qlbuf, Pbuf);
    k2_kernel<<<256, 256, 0, stream>>>(x, kbuf, qlbuf, Pbuf, gg, gl, out);
}

// Round 5
// 29.128 us; speedup vs baseline: 3.7543x; 1.2204x over previous
//
#include <hip/hip_runtime.h>

#define BSZ 4
#define CH  64
#define CE  8      // C/8
#define HW  4096
#define PJ  1088   // per-block partials: A 512 + B 512 + S 64

// ---------------------------------------------------------------------------
// K1: per block = (batch b, 64 columns p0..p0+63). 512 threads = 8 waves.
//  - conv: each thread holds its x column in 64 VGPRs; weights are read via
//    the SCALAR pipe (wave-uniform addresses -> s_load_dwordx16), so the LDS
//    pipe is untouched by the conv. 10 output channels per wave.
//  - k(8), q_l(8) -> global; k also -> kT LDS; v(64) -> vT LDS only.
//  - block-partial reduction (one e per wave):
//      A[e][c] = sum_pp vT[c][pp] * qgw[(p0+pp)*8+e]   (qgw via s_load)
//      B[e][c] = sum_pp vT[c][pp] * kT[e][pp]          (b128 broadcast)
//      S[c]    = sum_pp vT[c][pp] * qgb[p0+pp]         (wave 0 only)
//    -> own Pbuf slot (no atomics, no memset, coalesced stores).
// ---------------------------------------------------------------------------
__global__ __launch_bounds__(512) void k1_kernel(
    const float* __restrict__ x,
    const float* __restrict__ qlw, const float* __restrict__ qlb,
    const float* __restrict__ kw,  const float* __restrict__ kb,
    const float* __restrict__ vw,  const float* __restrict__ vb,
    const float* __restrict__ qgw, const float* __restrict__ qgb,
    float* __restrict__ kbuf, float* __restrict__ qlbuf, float* __restrict__ Pbuf)
{
    __shared__ float vT[CH][68];     // [channel][pp], pad->row stride 272B
    __shared__ float kT[CE][64];     // [e][pp]

    const int tid  = threadIdx.x;
    const int lane = tid & 63;
    const int g    = __builtin_amdgcn_readfirstlane(tid >> 6);  // wave 0..7
    const int b    = blockIdx.x >> 6;
    const int p0   = (blockIdx.x & 63) << 6;
    const int p    = p0 | lane;

    // x column into registers (64 coalesced 256B loads per wave)
    float xv[CH];
#pragma unroll
    for (int c = 0; c < CH; ++c) xv[c] = x[(((b << 6) + c) << 12) + p];

    // ---- conv: 10 channels per wave; weight rows via scalar pipe ----
    const int o0 = g * 10;           // scalar
#pragma unroll
    for (int i = 0; i < 10; ++i) {
        const int o = o0 + i;        // scalar 0..79
        const float* wr;
        float bias;
        if (o < 8)       { wr = kw  + (o << 6);        bias = kb[o]; }
        else if (o < 16) { wr = qlw + ((o - 8) << 6);  bias = qlb[o - 8]; }
        else             { wr = vw  + ((o - 16) << 6); bias = vb[o - 16]; }
        float acc = bias;
#pragma unroll
        for (int c = 0; c < CH; ++c) acc += wr[c] * xv[c];   // v_fmac v,s,v
        if (o < 8) {
            kbuf[(((b << 3) + o) << 12) + p] = acc;
            kT[o][lane] = acc;                    // lane-consecutive: no conflict
        } else if (o < 16) {
            qlbuf[(((b << 3) + (o - 8)) << 12) + p] = acc;
        } else {
            vT[o - 16][lane] = acc;               // lane-consecutive: no conflict
        }
    }
    __syncthreads();

    // ---- block-partial A/B/S: c = lane, e = g ----
    {
        const int e = g;             // scalar
        float a = 0.f, bb = 0.f;
#pragma unroll
        for (int pp = 0; pp < 64; pp += 4) {
            const float4 vv = *reinterpret_cast<const float4*>(&vT[lane][pp]);
            const float4 kk = *reinterpret_cast<const float4*>(&kT[e][pp]);
            const float w0 = qgw[((p0 + pp + 0) << 3) + e];   // s_load
            const float w1 = qgw[((p0 + pp + 1) << 3) + e];
            const float w2 = qgw[((p0 + pp + 2) << 3) + e];
            const float w3 = qgw[((p0 + pp + 3) << 3) + e];
            a  += vv.x * w0 + vv.y * w1 + vv.z * w2 + vv.w * w3;
            bb += vv.x * kk.x + vv.y * kk.y + vv.z * kk.z + vv.w * kk.w;
        }
        float* P = Pbuf + (size_t)blockIdx.x * PJ;
        P[(e << 6) + lane] = a;              // coalesced per wave
        P[512 + (e << 6) + lane] = bb;
        if (g == 0) {
            float s = 0.f;
#pragma unroll
            for (int pp = 0; pp < 64; pp += 4) {
                const float4 vv = *reinterpret_cast<const float4*>(&vT[lane][pp]);
                s += vv.x * qgb[p0 + pp] + vv.y * qgb[p0 + pp + 1]
                   + vv.z * qgb[p0 + pp + 2] + vv.w * qgb[p0 + pp + 3];
            }
            P[1024 + lane] = s;
        }
    }
}

// ---------------------------------------------------------------------------
// K2: per block = (batch b, 64 columns). 512 threads = 8 waves.
//  Phase A: reduce the 64 partial slots of this batch (L2-resident) -> LDS,
//           gg/gl folded in.
//  Phase B: out[b,c,p] = dot8(kg[p], ggA[c]) + ggS[c] + dot8(ql[p], glB[c]) + x
//           kg[b,p,e] = kbuf flat at b*32768 + p*8 + e (raw reshape regroup).
// ---------------------------------------------------------------------------
__global__ __launch_bounds__(512) void k2_kernel(
    const float* __restrict__ x,
    const float* __restrict__ kbuf, const float* __restrict__ qlbuf,
    const float* __restrict__ Pbuf,
    const float* __restrict__ ggp, const float* __restrict__ glp,
    float* __restrict__ out)
{
    __shared__ float sA[CH][8], sB[CH][8], sS[CH];
    const int tid  = threadIdx.x;
    const int lane = tid & 63;
    const int g    = __builtin_amdgcn_readfirstlane(tid >> 6);  // 0..7
    const int b    = blockIdx.x >> 6;
    const int p    = ((blockIdx.x & 63) << 6) | lane;
    const float gg = ggp[0], gl = glp[0];

    const float* Pb = Pbuf + (size_t)(b << 6) * PJ;
    for (int j = tid; j < PJ; j += 512) {
        float acc = 0.f;
#pragma unroll 16
        for (int s2 = 0; s2 < 64; ++s2) acc += Pb[(size_t)s2 * PJ + j];
        if (j < 512)       sA[j & 63][j >> 6] = gg * acc;
        else if (j < 1024) sB[j & 63][(j - 512) >> 6] = gl * acc;
        else               sS[j - 1024] = gg * acc;
    }

    // independent of LDS: issue before the barrier
    const float* kgp = kbuf + ((size_t)b << 15) + ((size_t)p << 3);
    const float4 kg0 = *reinterpret_cast<const float4*>(kgp);
    const float4 kg1 = *reinterpret_cast<const float4*>(kgp + 4);
    float ql[CE];
#pragma unroll
    for (int e = 0; e < CE; ++e) ql[e] = qlbuf[(((b << 3) + e) << 12) + p];

    __syncthreads();

    const int c0 = g << 3;   // scalar: 8 channels per wave
#pragma unroll
    for (int ci = 0; ci < 8; ++ci) {
        const int c = c0 + ci;   // scalar
        const float4 A0 = *reinterpret_cast<const float4*>(&sA[c][0]);
        const float4 A1 = *reinterpret_cast<const float4*>(&sA[c][4]);
        const float4 B0 = *reinterpret_cast<const float4*>(&sB[c][0]);
        const float4 B1 = *reinterpret_cast<const float4*>(&sB[c][4]);
        float r = sS[c];
        r += kg0.x * A0.x + kg0.y * A0.y + kg0.z * A0.z + kg0.w * A0.w;
        r += kg1.x * A1.x + kg1.y * A1.y + kg1.z * A1.z + kg1.w * A1.w;
        r += ql[0] * B0.x + ql[1] * B0.y + ql[2] * B0.z + ql[3] * B0.w;
        r += ql[4] * B1.x + ql[5] * B1.y + ql[6] * B1.z + ql[7] * B1.w;
        const int idx = (((b << 6) + c) << 12) + p;
        out[idx] = r + x[idx];
    }
}

extern "C" void kernel_launch(void* const* d_in, const int* in_sizes, int n_in,
                              void* d_out, int out_size, void* d_ws, size_t ws_size,
                              hipStream_t stream) {
    const float* x   = (const float*)d_in[0];
    const float* qlw = (const float*)d_in[1];
    const float* qlb = (const float*)d_in[2];
    const float* kw  = (const float*)d_in[3];
    const float* kb  = (const float*)d_in[4];
    const float* vw  = (const float*)d_in[5];
    const float* vb  = (const float*)d_in[6];
    const float* qgw = (const float*)d_in[7];
    const float* qgb = (const float*)d_in[8];
    const float* gg  = (const float*)d_in[9];
    const float* gl  = (const float*)d_in[10];
    float* out = (float*)d_out;

    float* ws    = (float*)d_ws;
    float* kbuf  = ws;                        // 4*8*4096 = 131072 f
    float* qlbuf = kbuf + BSZ * CE * HW;      // 131072 f
    float* Pbuf  = qlbuf + BSZ * CE * HW;     // 256*1088 = 278528 f

    k1_kernel<<<256, 512, 0, stream>>>(x, qlw, qlb, kw, kb, vw, vb, qgw, qgb,
                                       kbuf, qlbuf, Pbuf);
    k2_kernel<<<256, 512, 0, stream>>>(x, kbuf, qlbuf, Pbuf, gg, gl, out);
}